// Round 13
// baseline (354.062 us; speedup 1.0000x reference)
//
#include <hip/hip_runtime.h>

// Problem constants
constexpr int N_SITE    = 100000;
constexpr int N_VENDOR  = 20000;
constexpr int NE        = 3200000;
constexpr int SITE_IN   = 10;
constexpr int VENDOR_IN = 9;
constexpr int HID       = 64;
constexpr int OUT       = 32;

// Radix-build parameters (halved buckets vs r9: better stage2 occupancy)
constexpr int NBLK    = 1024;            // pass-1 grid (each block = one chunk)
constexpr int EPB     = NE / NBLK;       // 3125 edges per block
constexpr int SHIFT_S = 7;               // 128 sites per bucket
constexpr int NBUK_S  = (N_SITE + 127) / 128;    // 782
constexpr int SHIFT_V = 6;               // 64 vendors per bucket
constexpr int NBUK_V  = (N_VENDOR + 63) / 64;    // 313
static_assert(NBUK_S <= 1024 && NBUK_V <= 1024, "basescan assumes <=1024");

// Launch geometry
constexpr int SB1  = (N_SITE + 3) / 4;           // 25000 (gc2 site blocks)
constexpr int VB1  = (N_VENDOR + 3) / 4;         // 5000
constexpr int NS_BLK = (N_SITE + 15) / 16;       // 6250 (gc1fused site blocks)
constexpr int NV_BLK = (N_VENDOR + 15) / 16;     // 1250
constexpr int PADTOT = 16 * (N_SITE + N_VENDOR); // padded f16 feature elems

// ---------------------------------------------------------------------------
// Workspace layout (4-byte words).
constexpr long long I_OFF_V  = 0;                                // [N_VENDOR+1]
constexpr long long I_OFF_S  = I_OFF_V + N_VENDOR + 1;           // [N_SITE+1]
constexpr long long I_BASE_S = I_OFF_S + N_SITE + 1;             // [NBUK_S+1]
constexpr long long I_BASE_V = I_BASE_S + NBUK_S + 1;            // [NBUK_V+1]
constexpr long long I_TOT    = I_BASE_V + NBUK_V + 1;            // [NBUK_S+NBUK_V] zeroed/call
constexpr long long I_ADJ_V  = (I_TOT + NBUK_S + NBUK_V + 3) & ~3LL;  // [NE] int
constexpr long long I_ADJ_S  = I_ADJ_V + NE;                     // u16[NE] = NE/2 words
constexpr long long INT_END  = (I_ADJ_S + NE / 2 + 3) & ~3LL;
// Build scratch (h2 cursor tables + packed pairs).
constexpr long long A_H2S    = INT_END;                          // [NBLK*NBUK_S]
constexpr long long A_H2V    = A_H2S + (long long)NBLK * NBUK_S; // [NBLK*NBUK_V]
constexpr long long A_PAIRS  = (A_H2V + (long long)NBLK * NBUK_V + 3) & ~3LL;
constexpr long long BUILD_END = A_PAIRS + 2LL * NE;              // pairs_s + pairs_v (u32)
// f16 y tables (gc1fused -> gc2all), 64B rows (32 f16). Written after
// stage2both consumed pairs -> placed after BUILD_END (no aliasing).
constexpr long long F_Y16    = (BUILD_END + 3) & ~3LL;           // f16[(N_SITE+N_VENDOR)*32]
constexpr long long F_PAD    = F_Y16 + (long long)(N_SITE + N_VENDOR) * 16;
constexpr long long F_FUSED  = F_PAD + (long long)(N_SITE + N_VENDOR) * 8; // [4352]
constexpr long long WS_WORDS = F_FUSED + 4352;                   // ~61.4 MB

// fused sub-offsets (layer-1 matrices padded to 16 rows; pad rows are ZERO)
constexpr int F_M1SV = 0;      // 16x64  W_site_in@Wl1sv   (rows 10..15 = 0)
constexpr int F_M1VS = 1024;   // 16x64  W_vendor_in@Wl1vs (rows 9..15 = 0)
constexpr int F_R1SV = 2048;   // 16x64  W_vendor_in@Wr1sv
constexpr int F_R1VS = 3072;   // 16x64  W_site_in@Wr1vs
constexpr int F_V1SV = 4096;   // 64     b_site_in@Wl1sv
constexpr int F_V1VS = 4160;   // 64     b_vendor_in@Wl1vs
constexpr int F_r1SV = 4224;   // 64     b_vendor_in@Wr1sv
constexpr int F_r1VS = 4288;   // 64     b_site_in@Wr1vs

// ---------------------------------------------------------------------------
// f16 helpers. v_dot2_f32_f16 (fp32 accumulate of an f16 pair product) when
// available; cvt+fma fallback.
typedef _Float16 h2_t __attribute__((ext_vector_type(2)));
__device__ __forceinline__ h2_t as_h2(unsigned u) {
    union { unsigned u; h2_t h; } c; c.u = u; return c.h;
}
__device__ __forceinline__ unsigned short f2h(float f) {
    union { _Float16 h; unsigned short u; } c; c.h = (_Float16)f; return c.u;
}
#if defined(__has_builtin)
#if __has_builtin(__builtin_amdgcn_fdot2)
#define HAVE_FDOT2 1
#endif
#endif
__device__ __forceinline__ void acc2(float& slo, float& shi, unsigned u) {
#ifdef HAVE_FDOT2
    h2_t sel_lo = {(_Float16)1.0f, (_Float16)0.0f};
    h2_t sel_hi = {(_Float16)0.0f, (_Float16)1.0f};
    slo = __builtin_amdgcn_fdot2(as_h2(u), sel_lo, slo, false);
    shi = __builtin_amdgcn_fdot2(as_h2(u), sel_hi, shi, false);
#else
    h2_t h = as_h2(u);
    slo += (float)h.x; shi += (float)h.y;
#endif
}
__device__ __forceinline__ float ddot2(unsigned a, unsigned b, float c) {
#ifdef HAVE_FDOT2
    return __builtin_amdgcn_fdot2(as_h2(a), as_h2(b), c, false);
#else
    h2_t ha = as_h2(a), hb = as_h2(b);
    return c + (float)ha.x * (float)hb.x + (float)ha.y * (float)hb.y;
#endif
}

// ---------------------------------------------------------------------------
// Merged prep: pad raw features to 16 f16/row AND fold input-projection +
// layer-1 weights into padded fused matrices (one launch).
__global__ __launch_bounds__(256) void prep(
        const float* __restrict__ x_site, const float* __restrict__ x_vendor,
        unsigned short* __restrict__ xsp, unsigned short* __restrict__ xvp,
        const float* __restrict__ Wsi, const float* __restrict__ bsi,
        const float* __restrict__ Wvi, const float* __restrict__ bvi,
        const float* __restrict__ Wl1sv, const float* __restrict__ Wr1sv,
        const float* __restrict__ Wl1vs, const float* __restrict__ Wr1vs,
        float* __restrict__ fused) {
    long long t = (long long)blockIdx.x * 256 + threadIdx.x;
    if (t < (long long)N_SITE * 16) {
        int i = (int)(t >> 4), k = (int)(t & 15);
        xsp[t] = f2h(k < SITE_IN ? x_site[i * SITE_IN + k] : 0.f);
        return;
    }
    t -= (long long)N_SITE * 16;
    if (t < (long long)N_VENDOR * 16) {
        int i = (int)(t >> 4), k = (int)(t & 15);
        xvp[t] = f2h(k < VENDOR_IN ? x_vendor[i * VENDOR_IN + k] : 0.f);
        return;
    }
    t -= (long long)N_VENDOR * 16;
    int idx = (int)t;
    if (idx < 4096) {                       // matrices, m = 0..3 (16x64 each)
        int m = idx >> 10, rem = idx & 1023, r = rem >> 6, c = rem & 63;
        int K = (m == 0 || m == 3) ? SITE_IN : VENDOR_IN;
        const float* A = (m == 0 || m == 3) ? Wsi : Wvi;
        const float* B = (m == 0) ? Wl1sv : (m == 1) ? Wl1vs : (m == 2) ? Wr1sv : Wr1vs;
        float s = 0.f;
        if (r < K)
            for (int j = 0; j < 64; ++j) s = fmaf(A[r * 64 + j], B[j * 64 + c], s);
        fused[idx] = s;
    } else if (idx < 4352) {                // bias vectors
        int m = (idx - 4096) >> 6, c = idx & 63;
        const float* a = (m == 0 || m == 3) ? bsi : bvi;
        const float* B = (m == 0) ? Wl1sv : (m == 1) ? Wl1vs : (m == 2) ? Wr1sv : Wr1vs;
        float s = 0.f;
        for (int j = 0; j < 64; ++j) s = fmaf(a[j], B[j * 64 + c], s);
        fused[idx] = s;
    }
}

// ---------------------------------------------------------------------------
// Build K1: per-block LDS bucket histograms for BOTH directions in one edge
// read. Writes private h2 rows (no atomics) + merges bucket totals.
__global__ __launch_bounds__(256) void histbk(const int* __restrict__ src,
                                              const int* __restrict__ dst,
                                              int* __restrict__ h2s,
                                              int* __restrict__ h2v,
                                              int* __restrict__ tot) {
    __shared__ int hs[NBUK_S];
    __shared__ int hv[NBUK_V];
    int blk = blockIdx.x, tid = threadIdx.x;
    for (int i = tid; i < NBUK_S; i += 256) hs[i] = 0;
    for (int i = tid; i < NBUK_V; i += 256) hv[i] = 0;
    __syncthreads();
    int lo = blk * EPB;
    for (int e = lo + tid; e < lo + EPB; e += 256) {
        atomicAdd(&hs[src[e] >> SHIFT_S], 1);
        atomicAdd(&hv[dst[e] >> SHIFT_V], 1);
    }
    __syncthreads();
    for (int i = tid; i < NBUK_S; i += 256) {
        int c = hs[i];
        h2s[(long long)blk * NBUK_S + i] = c;
        if (c) atomicAdd(&tot[i], c);
    }
    for (int i = tid; i < NBUK_V; i += 256) {
        int c = hv[i];
        h2v[(long long)blk * NBUK_V + i] = c;
        if (c) atomicAdd(&tot[NBUK_S + i], c);
    }
}

// Build K2: exclusive scan of bucket totals -> bucket base offsets (1024 thr).
__global__ __launch_bounds__(1024) void basescan(const int* __restrict__ tot,
                                                 int* __restrict__ base_s,
                                                 int* __restrict__ base_v) {
    __shared__ int a[1024];
    int tid = threadIdx.x;
    int v = (tid < NBUK_S) ? tot[tid] : 0;
    a[tid] = v; __syncthreads();
    for (int st = 1; st < 1024; st <<= 1) {
        int x = (tid >= st) ? a[tid - st] : 0; __syncthreads();
        a[tid] += x; __syncthreads();
    }
    if (tid < NBUK_S) base_s[tid] = a[tid] - v;
    if (tid == 0) base_s[NBUK_S] = NE;
    __syncthreads();
    int w = (tid < NBUK_V) ? tot[NBUK_S + tid] : 0;
    a[tid] = w; __syncthreads();
    for (int st = 1; st < 1024; st <<= 1) {
        int x = (tid >= st) ? a[tid - st] : 0; __syncthreads();
        a[tid] += x; __syncthreads();
    }
    if (tid < NBUK_V) base_v[tid] = a[tid] - w;
    if (tid == 0) base_v[NBUK_V] = NE;
}

// Build K3: convert h2 counts into per-(chunk,bucket) write cursors.
__global__ __launch_bounds__(256) void cursorize(int* __restrict__ h2s,
                                                 int* __restrict__ h2v,
                                                 const int* __restrict__ base_s,
                                                 const int* __restrict__ base_v) {
    int b = blockIdx.x, tid = threadIdx.x;
    int* h2; const int* base; int nbuk;
    if (b < NBUK_S) { h2 = h2s; base = base_s; nbuk = NBUK_S; }
    else            { b -= NBUK_S; h2 = h2v; base = base_v; nbuk = NBUK_V; }
    int c[4], loc[4], s = 0;
    #pragma unroll
    for (int i = 0; i < 4; ++i) c[i] = h2[(long long)(tid * 4 + i) * nbuk + b];
    #pragma unroll
    for (int i = 0; i < 4; ++i) { loc[i] = s; s += c[i]; }
    __shared__ int p[256];
    p[tid] = s; __syncthreads();
    for (int st = 1; st < 256; st <<= 1) {
        int x = (tid >= st) ? p[tid - st] : 0; __syncthreads();
        p[tid] += x; __syncthreads();
    }
    int pre = base[b] + (tid ? p[tid - 1] : 0);
    #pragma unroll
    for (int i = 0; i < 4; ++i) h2[(long long)(tid * 4 + i) * nbuk + b] = pre + loc[i];
}

// Build K4: scatter PACKED 4-byte pairs for BOTH directions in one edge read.
// site pair:   (site&127)<<25 | vendor   (vendor < 2^15)
// vendor pair: (vendor&63)<<26 | site    (site < 2^17)
__global__ __launch_bounds__(256) void scatter_both(
        const int* __restrict__ src, const int* __restrict__ dst,
        const int* __restrict__ h2s, const int* __restrict__ h2v,
        unsigned* __restrict__ pairs_s, unsigned* __restrict__ pairs_v) {
    __shared__ int cs[NBUK_S];
    __shared__ int cv[NBUK_V];
    int blk = blockIdx.x, tid = threadIdx.x;
    for (int i = tid; i < NBUK_S; i += 256) cs[i] = h2s[(long long)blk * NBUK_S + i];
    for (int i = tid; i < NBUK_V; i += 256) cv[i] = h2v[(long long)blk * NBUK_V + i];
    __syncthreads();
    int lo = blk * EPB;
    for (int e = lo + tid; e < lo + EPB; e += 256) {
        int s = src[e], d = dst[e];
        int ps = atomicAdd(&cs[s >> SHIFT_S], 1);
        pairs_s[ps] = ((unsigned)(s & 127) << 25) | (unsigned)d;
        int pv = atomicAdd(&cv[d >> SHIFT_V], 1);
        pairs_v[pv] = ((unsigned)(d & 63) << 26) | (unsigned)s;
    }
}

// Build K5: per-bucket counting sort for BOTH directions (grid-split).
__global__ __launch_bounds__(256) void stage2both(
        const unsigned* __restrict__ pairs_s, const unsigned* __restrict__ pairs_v,
        const int* __restrict__ base_s, const int* __restrict__ base_v,
        int* __restrict__ off_s, int* __restrict__ off_v,
        unsigned short* __restrict__ adj_s16, int* __restrict__ adj_v) {
    int b = blockIdx.x, tid = threadIdx.x;
    bool site = (b < NBUK_S);
    const unsigned* pairs; const int* base; int* off;
    int BW, nnode, shloc, lo_node;
    if (site) {
        pairs = pairs_s; base = base_s; off = off_s;
        BW = 128; nnode = N_SITE; shloc = 25; lo_node = b << SHIFT_S;
    } else {
        b -= NBUK_S;
        pairs = pairs_v; base = base_v; off = off_v;
        BW = 64; nnode = N_VENDOR; shloc = 26; lo_node = b << SHIFT_V;
    }
    int p0 = base[b], p1 = base[b + 1];
    __shared__ int deg[128];
    __shared__ int cur[128];
    __shared__ int sc[256];
    if (tid < BW) deg[tid] = 0;
    __syncthreads();
    for (int e = p0 + tid; e < p1; e += 256)
        atomicAdd(&deg[(int)(pairs[e] >> shloc)], 1);
    __syncthreads();
    int d = (tid < BW) ? deg[tid] : 0;
    sc[tid] = d;
    __syncthreads();
    for (int st = 1; st < 256; st <<= 1) {
        int x = (tid >= st) ? sc[tid - st] : 0; __syncthreads();
        sc[tid] += x; __syncthreads();
    }
    int excl = sc[tid] - d;
    if (tid < BW) {
        int node = lo_node + tid;
        if (node < nnode) off[node] = p0 + excl;
        cur[tid] = p0 + excl;
    }
    if (tid == 0) {
        if (site && b == NBUK_S - 1) off_s[N_SITE] = NE;
        if (!site && b == NBUK_V - 1) off_v[N_VENDOR] = NE;
    }
    __syncthreads();
    if (site) {
        for (int e = p0 + tid; e < p1; e += 256) {
            unsigned p = pairs[e];
            int pos = atomicAdd(&cur[(int)(p >> 25)], 1);
            adj_s16[pos] = (unsigned short)p;           // vendor id < 2^15
        }
    } else {
        for (int e = p0 + tid; e < p1; e += 256) {
            unsigned p = pairs[e];
            int pos = atomicAdd(&cur[(int)(p >> 26)], 1);
            adj_v[pos] = (int)(p & 0x3FFFFFFu);         // site id < 2^17
        }
    }
}

// ---------------------------------------------------------------------------
// Layer-1 gather helper: 16 lanes per node; f16 rows, fdot2 accumulate.
template<typename IdxT>
__device__ __forceinline__ void gather1(const unsigned short* __restrict__ fp,
                                        const IdxT* __restrict__ adj,
                                        int lo, int hi, int l16, float* s) {
    for (int j = lo + l16; j < hi; j += 16) {
        const unsigned short* row = fp + (long long)adj[j] * 16;
        uint4 q0 = *(const uint4*)row;
        unsigned u4 = *(const unsigned*)(row + 8);
        acc2(s[0], s[1], q0.x);
        acc2(s[2], s[3], q0.y);
        acc2(s[4], s[5], q0.z);
        acc2(s[6], s[7], u4);   // note: order of s[] pairs fixed below
        // (see call site: mapping corrected there)
    }
}

// NOTE: gather1 above packs q0.w/u4 — keep explicit version to avoid mapping
// bugs; the real gather is inlined below.
template<typename IdxT>
__device__ __forceinline__ void gather1x(const unsigned short* __restrict__ fp,
                                         const IdxT* __restrict__ adj,
                                         int lo, int hi, int l16, float* s) {
    for (int j = lo + l16; j < hi; j += 16) {
        const unsigned short* row = fp + (long long)adj[j] * 16;
        uint4 q0 = *(const uint4*)row;
        unsigned u4 = *(const unsigned*)(row + 8);
        acc2(s[0], s[1], q0.x);
        acc2(s[2], s[3], q0.y);
        acc2(s[4], s[5], q0.z);
        acc2(s[6], s[7], q0.w);
        acc2(s[8], s[9], u4);
    }
}

// Fused layer-1 + layer-2 projection. Block = 256 threads = 16 nodes
// (16 lanes/node). Stage B: gather padded f16 neighbor rows, 4-step
// butterfly, fused mean-project + fp32 self-project + relu -> x1 (f16 pairs)
// into LDS. Stage C: [y|z] = x1 @ [Wl2|Wr2] via v_dot2_f32_f16 from f16-pair
// LDS (half the LDS bytes/instructions of the fp32 version); y -> f16 table
// (64B rows), z -> fp32 directly into d_out (self term; gc2all RMWs it).
__global__ __launch_bounds__(256) void gc1fused(
        const unsigned short* __restrict__ xsp, const unsigned short* __restrict__ xvp,
        const float* __restrict__ xs_raw, const float* __restrict__ xv_raw,
        const int* __restrict__ off_s, const unsigned short* __restrict__ adj_s16,
        const int* __restrict__ off_v, const int* __restrict__ adj_v,
        const float* __restrict__ fused,
        const float* __restrict__ bl1vs, const float* __restrict__ bl1sv,
        const float* __restrict__ Wl2sv, const float* __restrict__ Wr2vs,
        const float* __restrict__ Wl2vs, const float* __restrict__ Wr2sv,
        unsigned short* __restrict__ ys16, unsigned short* __restrict__ yv16,
        float* __restrict__ out) {
    __shared__ unsigned sWp[32 * 64];   // [kk][c]: f16 pair (W[2kk][c], W[2kk+1][c])
    __shared__ unsigned sXp[16][34];    // [node][kk]: f16 pair (x[2kk], x[2kk+1])
    int b = blockIdx.x, tid = threadIdx.x;
    bool site = (b < NS_BLK);
    const float *fsraw, *M, *V, *BL, *R, *RV, *Wl, *Wr;
    const int* off;
    unsigned short* Y; float* Z;
    int nodebase, n, kx;
    if (site) {          // site node: aggregate vendor feats, self = site feats
        nodebase = b * 16; n = N_SITE; kx = SITE_IN;
        fsraw = xs_raw; off = off_s;
        M = fused + F_M1VS; V = fused + F_V1VS; BL = bl1vs;
        R = fused + F_R1VS; RV = fused + F_r1VS;
        Wl = Wl2sv; Wr = Wr2vs; Y = ys16; Z = out;
    } else {             // vendor node
        nodebase = (b - NS_BLK) * 16; n = N_VENDOR; kx = VENDOR_IN;
        fsraw = xv_raw; off = off_v;
        M = fused + F_M1SV; V = fused + F_V1SV; BL = bl1sv;
        R = fused + F_R1SV; RV = fused + F_r1SV;
        Wl = Wl2vs; Wr = Wr2sv; Y = yv16;
        Z = out + (long long)N_SITE * OUT;
    }
    // stage W into LDS as f16 k-pairs
    for (int i = tid; i < 2048; i += 256) {
        int kk = i >> 6, c = i & 63;
        int k0 = kk * 2, k1 = k0 + 1;
        float w0 = (c < 32) ? Wl[k0 * 32 + c] : Wr[k0 * 32 + (c - 32)];
        float w1 = (c < 32) ? Wl[k1 * 32 + c] : Wr[k1 * 32 + (c - 32)];
        sWp[i] = (unsigned)f2h(w0) | ((unsigned)f2h(w1) << 16);
    }
    // ---- Stage B: layer-1 for this thread's node (16 lanes/node) ----
    int l16 = tid & 15, nib = tid >> 4;
    int w = nodebase + nib;
    int c0 = l16 * 4;
    if (w < n) {
        int lo = off[w], hi = off[w + 1], deg = hi - lo;
        float s[10];
        #pragma unroll
        for (int k = 0; k < 10; ++k) s[k] = 0.f;
        if (site) gather1x(xvp, adj_s16, lo, hi, l16, s);
        else      gather1x(xsp, adj_v,   lo, hi, l16, s);
        #pragma unroll
        for (int k = 0; k < 10; ++k) {
            s[k] += __shfl_xor(s[k], 1, 64);
            s[k] += __shfl_xor(s[k], 2, 64);
            s[k] += __shfl_xor(s[k], 4, 64);
            s[k] += __shfl_xor(s[k], 8, 64);
        }
        float inv = 1.0f / (float)max(deg, 1);
        float4 acc = *(const float4*)(BL + c0);
        float4 rv4 = *(const float4*)(RV + c0);
        acc.x += rv4.x; acc.y += rv4.y; acc.z += rv4.z; acc.w += rv4.w;
        if (deg > 0) {
            float4 v4 = *(const float4*)(V + c0);
            acc.x += v4.x; acc.y += v4.y; acc.z += v4.z; acc.w += v4.w;
        }
        #pragma unroll
        for (int k = 0; k < 10; ++k) {
            float m = s[k] * inv;
            float4 m4 = *(const float4*)(M + k * 64 + c0);
            acc.x = fmaf(m, m4.x, acc.x);
            acc.y = fmaf(m, m4.y, acc.y);
            acc.z = fmaf(m, m4.z, acc.z);
            acc.w = fmaf(m, m4.w, acc.w);
        }
        const float* xr = fsraw + (long long)w * kx;   // broadcast fp32 self row
        for (int k = 0; k < kx; ++k) {
            float xv = xr[k];
            float4 r4 = *(const float4*)(R + k * 64 + c0);
            acc.x = fmaf(xv, r4.x, acc.x);
            acc.y = fmaf(xv, r4.y, acc.y);
            acc.z = fmaf(xv, r4.z, acc.z);
            acc.w = fmaf(xv, r4.w, acc.w);
        }
        unsigned plo = (unsigned)f2h(fmaxf(acc.x, 0.f)) |
                       ((unsigned)f2h(fmaxf(acc.y, 0.f)) << 16);
        unsigned phi = (unsigned)f2h(fmaxf(acc.z, 0.f)) |
                       ((unsigned)f2h(fmaxf(acc.w, 0.f)) << 16);
        *(uint2*)&sXp[nib][l16 * 2] = make_uint2(plo, phi);
    }
    __syncthreads();
    // ---- Stage C: [y|z] = x1 @ [Wl|Wr] via dot2 (32 k-pair iters) ----
    int n2 = tid >> 4, q = tid & 15;   // node, col-group (cols 4q..4q+3)
    int node = nodebase + n2;
    float4 acc = {0.f, 0.f, 0.f, 0.f};
    const unsigned* xrow = sXp[n2];
    #pragma unroll 8
    for (int kk = 0; kk < 32; ++kk) {
        unsigned xp = xrow[kk];                       // LDS broadcast / 16 thr
        uint4 wp = *(const uint4*)(sWp + kk * 64 + q * 4);
        acc.x = ddot2(xp, wp.x, acc.x);
        acc.y = ddot2(xp, wp.y, acc.y);
        acc.z = ddot2(xp, wp.z, acc.z);
        acc.w = ddot2(xp, wp.w, acc.w);
    }
    if (node < n) {
        if (q < 8) {
            unsigned p01 = (unsigned)f2h(acc.x) | ((unsigned)f2h(acc.y) << 16);
            unsigned p23 = (unsigned)f2h(acc.z) | ((unsigned)f2h(acc.w) << 16);
            *(uint2*)(Y + (long long)node * 32 + q * 4) = make_uint2(p01, p23);
        } else {
            *(float4*)(Z + (long long)node * 32 + (q - 8) * 4) = acc;
        }
    }
}

// ---------------------------------------------------------------------------
// Layer-2 gather helper: 8 edge-groups x 8 lanes; each lane covers 4 f16
// cols via one uint2 per edge (8 load-instructions per 64B row).
template<typename IdxT>
__device__ __forceinline__ void gather2(const unsigned short* __restrict__ y,
                                        const IdxT* __restrict__ adj,
                                        int lo, int deg, int g, int q,
                                        float& s0, float& s1, float& s2, float& s3) {
    int m = (deg > g) ? ((deg - g + 7) >> 3) : 0;
    const IdxT* ap = adj + lo + g;
    int t = 0;
    for (; t + 2 <= m; t += 2) {
        long long a0 = (long long)ap[8 * t];
        long long a1 = (long long)ap[8 * t + 8];
        uint2 u0 = *(const uint2*)(y + a0 * 32 + 4 * q);
        uint2 u1 = *(const uint2*)(y + a1 * 32 + 4 * q);
        acc2(s0, s1, u0.x); acc2(s2, s3, u0.y);
        acc2(s0, s1, u1.x); acc2(s2, s3, u1.y);
    }
    if (t < m) {
        long long a0 = (long long)ap[8 * t];
        uint2 u0 = *(const uint2*)(y + a0 * 32 + 4 * q);
        acc2(s0, s1, u0.x); acc2(s2, s3, u0.y);
    }
}

// Merged layer-2 combine: out = relu(gather_mean(f16 y) + b + z) where z was
// pre-written into d_out by gc1fused. One wave per node.
__global__ __launch_bounds__(256) void gc2all(
        const unsigned short* __restrict__ ys16, const unsigned short* __restrict__ yv16,
        const int* __restrict__ off_s, const unsigned short* __restrict__ adj_s16,
        const int* __restrict__ off_v, const int* __restrict__ adj_v,
        const float* __restrict__ bl2vs, const float* __restrict__ bl2sv,
        float* __restrict__ out) {
    int b = blockIdx.x;
    bool site = (b < SB1);
    const float* bias; const int* off; float* o; int w, n;
    if (site) {          // site outputs gather vendor pre-projections
        w = b * 4 + (threadIdx.x >> 6); n = N_SITE;
        off = off_s; bias = bl2vs; o = out;
    } else {
        w = (b - SB1) * 4 + (threadIdx.x >> 6); n = N_VENDOR;
        off = off_v; bias = bl2sv;
        o = out + (long long)N_SITE * OUT;
    }
    if (w >= n) return;
    int lane = threadIdx.x & 63, g = lane >> 3, q = lane & 7;
    int lo = off[w], hi = off[w + 1], deg = hi - lo;
    float s0 = 0.f, s1 = 0.f, s2 = 0.f, s3 = 0.f;
    if (site) gather2(yv16, adj_s16, lo, deg, g, q, s0, s1, s2, s3);
    else      gather2(ys16, adj_v,   lo, deg, g, q, s0, s1, s2, s3);
    #pragma unroll
    for (int m = 8; m <= 32; m <<= 1) {
        s0 += __shfl_xor(s0, m, 64);
        s1 += __shfl_xor(s1, m, 64);
        s2 += __shfl_xor(s2, m, 64);
        s3 += __shfl_xor(s3, m, 64);
    }
    if (g == 0) {
        float inv = 1.0f / (float)max(deg, 1);
        float4 bz = *(const float4*)(bias + 4 * q);
        long long oi = (long long)w * 32 + 4 * q;
        float4 z = *(const float4*)(o + oi);
        float4 r;
        r.x = fmaxf(fmaf(s0, inv, bz.x + z.x), 0.f);
        r.y = fmaxf(fmaf(s1, inv, bz.y + z.y), 0.f);
        r.z = fmaxf(fmaf(s2, inv, bz.z + z.z), 0.f);
        r.w = fmaxf(fmaf(s3, inv, bz.w + z.w), 0.f);
        *(float4*)(o + oi) = r;
    }
}

// ---------------------------------------------------------------------------
extern "C" void kernel_launch(void* const* d_in, const int* in_sizes, int n_in,
                              void* d_out, int out_size, void* d_ws, size_t ws_size,
                              hipStream_t stream) {
    const float* x_site      = (const float*)d_in[0];
    const float* x_vendor    = (const float*)d_in[1];
    const int*   src         = (const int*)d_in[2];
    const int*   dst         = (const int*)d_in[3];
    const float* W_site_in   = (const float*)d_in[4];
    const float* b_site_in   = (const float*)d_in[5];
    const float* W_vendor_in = (const float*)d_in[6];
    const float* b_vendor_in = (const float*)d_in[7];
    const float* Wl1sv = (const float*)d_in[8];
    const float* bl1sv = (const float*)d_in[9];
    const float* Wr1sv = (const float*)d_in[10];
    const float* Wl1vs = (const float*)d_in[11];
    const float* bl1vs = (const float*)d_in[12];
    const float* Wr1vs = (const float*)d_in[13];
    const float* Wl2sv = (const float*)d_in[14];
    const float* bl2sv = (const float*)d_in[15];
    const float* Wr2sv = (const float*)d_in[16];
    const float* Wl2vs = (const float*)d_in[17];
    const float* bl2vs = (const float*)d_in[18];
    const float* Wr2vs = (const float*)d_in[19];

    // Guard: never write past harness scratch (overrun can kill the container).
    if (ws_size < (size_t)WS_WORDS * 4) return;

    int*   wi  = (int*)d_ws;
    float* wf  = (float*)d_ws;
    float* out = (float*)d_out;

    int* off_v  = wi + I_OFF_V;
    int* off_s  = wi + I_OFF_S;
    int* base_s = wi + I_BASE_S;
    int* base_v = wi + I_BASE_V;
    int* tot    = wi + I_TOT;
    int* adj_v  = wi + I_ADJ_V;
    unsigned short* adj_s16 = (unsigned short*)(wi + I_ADJ_S);
    int* h2s    = wi + A_H2S;
    int* h2v    = wi + A_H2V;
    unsigned* pairs_s = (unsigned*)(wi + A_PAIRS);
    unsigned* pairs_v = pairs_s + NE;
    unsigned short* ys16 = (unsigned short*)(wf + F_Y16);
    unsigned short* yv16 = ys16 + (long long)N_SITE * 32;
    unsigned short* xsp  = (unsigned short*)(wf + F_PAD);
    unsigned short* xvp  = xsp + (long long)N_SITE * 16;
    float* fused = wf + F_FUSED;

    // zero bucket totals (ws not re-poisoned between replays; zero every call)
    hipMemsetAsync(tot, 0, (size_t)(NBUK_S + NBUK_V) * sizeof(int), stream);

    // merged pad + weight-fold
    prep<<<(PADTOT + 4352 + 255) / 256, 256, 0, stream>>>(
        x_site, x_vendor, xsp, xvp,
        W_site_in, b_site_in, W_vendor_in, b_vendor_in,
        Wl1sv, Wr1sv, Wl1vs, Wr1vs, fused);

    // --- CSR build: two-level radix, packed 4B pairs, u16 site adjacency ---
    histbk<<<NBLK, 256, 0, stream>>>(src, dst, h2s, h2v, tot);
    basescan<<<1, 1024, 0, stream>>>(tot, base_s, base_v);
    cursorize<<<NBUK_S + NBUK_V, 256, 0, stream>>>(h2s, h2v, base_s, base_v);
    scatter_both<<<NBLK, 256, 0, stream>>>(src, dst, h2s, h2v, pairs_s, pairs_v);
    stage2both<<<NBUK_S + NBUK_V, 256, 0, stream>>>(pairs_s, pairs_v, base_s, base_v,
                                                    off_s, off_v, adj_s16, adj_v);

    // --- layer 1 + layer-2 projection, fully fused (both directions) ---
    gc1fused<<<NS_BLK + NV_BLK, 256, 0, stream>>>(
        xsp, xvp, x_site, x_vendor, off_s, adj_s16, off_v, adj_v,
        fused, bl1vs, bl1sv, Wl2sv, Wr2vs, Wl2vs, Wr2sv,
        ys16, yv16, out);

    // --- layer 2: merged gather+mean+bias+self+relu ---
    gc2all<<<SB1 + VB1, 256, 0, stream>>>(ys16, yv16, off_s, adj_s16, off_v, adj_v,
                                          bl2vs, bl2sv, out);

    (void)in_sizes; (void)n_in; (void)out_size;
}

// Round 14
// 326.033 us; speedup vs baseline: 1.0860x; 1.0860x over previous
//
#include <hip/hip_runtime.h>

// Problem constants
constexpr int N_SITE    = 100000;
constexpr int N_VENDOR  = 20000;
constexpr int NE        = 3200000;
constexpr int SITE_IN   = 10;
constexpr int VENDOR_IN = 9;
constexpr int HID       = 64;
constexpr int OUT       = 32;

// Radix-build parameters: fixed-capacity buckets (mean site bucket = 4096
// edges, sigma 64 -> CAP_S = +16 sigma; vendor mean 10240, sigma 101 ->
// CAP_V = +20 sigma). Overflow is statistically impossible for uniform
// random edges; writes are clamped defensively.
constexpr int NBLK    = 1024;            // scatter grid (each block = one chunk)
constexpr int EPB     = NE / NBLK;       // 3125 edges per block
constexpr int SHIFT_S = 7;               // 128 sites per bucket
constexpr int NBUK_S  = (N_SITE + 127) / 128;    // 782
constexpr int CAP_S   = 5120;
constexpr int SHIFT_V = 6;               // 64 vendors per bucket
constexpr int NBUK_V  = (N_VENDOR + 63) / 64;    // 313
constexpr int CAP_V   = 12288;

// Launch geometry
constexpr int SB1  = (N_SITE + 3) / 4;           // 25000 (gc2 site blocks)
constexpr int VB1  = (N_VENDOR + 3) / 4;         // 5000
constexpr int NS_BLK = (N_SITE + 15) / 16;       // 6250 (gc1fused site blocks)
constexpr int NV_BLK = (N_VENDOR + 15) / 16;     // 1250
constexpr int PADTOT = 16 * (N_SITE + N_VENDOR); // padded f16 feature elems

// ---------------------------------------------------------------------------
// Workspace layout (4-byte words).
constexpr long long I_NSTART_S = 0;                               // [N_SITE]
constexpr long long I_NDEG_S   = I_NSTART_S + N_SITE;             // [N_SITE]
constexpr long long I_NSTART_V = I_NDEG_S + N_SITE;               // [N_VENDOR]
constexpr long long I_NDEG_V   = I_NSTART_V + N_VENDOR;           // [N_VENDOR]
constexpr long long I_GCUR     = I_NDEG_V + N_VENDOR;             // [NBUK_S+NBUK_V] zero/call
constexpr long long I_ADJ_V    = (I_GCUR + NBUK_S + NBUK_V + 3) & ~3LL; // [NBUK_V*CAP_V] int
constexpr long long I_ADJ_S    = I_ADJ_V + (long long)NBUK_V * CAP_V;   // u16[NBUK_S*CAP_S]
constexpr long long INT_END    = (I_ADJ_S + (long long)NBUK_S * CAP_S / 2 + 3) & ~3LL;
constexpr long long A_PAIRS_S  = INT_END;                         // [NBUK_S*CAP_S] u32
constexpr long long A_PAIRS_V  = A_PAIRS_S + (long long)NBUK_S * CAP_S;
constexpr long long BUILD_END  = A_PAIRS_V + (long long)NBUK_V * CAP_V;
// f16 y tables (gc1fused -> gc2all), 64B rows (32 f16). Written after
// stage2both consumed pairs -> placed after BUILD_END (no aliasing).
constexpr long long F_Y16    = (BUILD_END + 3) & ~3LL;
constexpr long long F_PAD    = F_Y16 + (long long)(N_SITE + N_VENDOR) * 16;
constexpr long long F_FUSED  = F_PAD + (long long)(N_SITE + N_VENDOR) * 8; // [4352]
constexpr long long WS_WORDS = F_FUSED + 4352;                   // ~67.4 MB

// fused sub-offsets (layer-1 matrices padded to 16 rows; pad rows are ZERO)
constexpr int F_M1SV = 0;      // 16x64  W_site_in@Wl1sv   (rows 10..15 = 0)
constexpr int F_M1VS = 1024;   // 16x64  W_vendor_in@Wl1vs (rows 9..15 = 0)
constexpr int F_R1SV = 2048;   // 16x64  W_vendor_in@Wr1sv
constexpr int F_R1VS = 3072;   // 16x64  W_site_in@Wr1vs
constexpr int F_V1SV = 4096;   // 64     b_site_in@Wl1sv
constexpr int F_V1VS = 4160;   // 64     b_vendor_in@Wl1vs
constexpr int F_r1SV = 4224;   // 64     b_vendor_in@Wr1sv
constexpr int F_r1VS = 4288;   // 64     b_site_in@Wr1vs

// ---------------------------------------------------------------------------
// f16 helpers. v_dot2_f32_f16 when available; cvt+fma fallback.
typedef _Float16 h2_t __attribute__((ext_vector_type(2)));
__device__ __forceinline__ h2_t as_h2(unsigned u) {
    union { unsigned u; h2_t h; } c; c.u = u; return c.h;
}
__device__ __forceinline__ unsigned short f2h(float f) {
    union { _Float16 h; unsigned short u; } c; c.h = (_Float16)f; return c.u;
}
#if defined(__has_builtin)
#if __has_builtin(__builtin_amdgcn_fdot2)
#define HAVE_FDOT2 1
#endif
#endif
__device__ __forceinline__ void acc2(float& slo, float& shi, unsigned u) {
#ifdef HAVE_FDOT2
    h2_t sel_lo = {(_Float16)1.0f, (_Float16)0.0f};
    h2_t sel_hi = {(_Float16)0.0f, (_Float16)1.0f};
    slo = __builtin_amdgcn_fdot2(as_h2(u), sel_lo, slo, false);
    shi = __builtin_amdgcn_fdot2(as_h2(u), sel_hi, shi, false);
#else
    h2_t h = as_h2(u);
    slo += (float)h.x; shi += (float)h.y;
#endif
}
__device__ __forceinline__ float ddot2(unsigned a, unsigned b, float c) {
#ifdef HAVE_FDOT2
    return __builtin_amdgcn_fdot2(as_h2(a), as_h2(b), c, false);
#else
    h2_t ha = as_h2(a), hb = as_h2(b);
    return c + (float)ha.x * (float)hb.x + (float)ha.y * (float)hb.y;
#endif
}

// ---------------------------------------------------------------------------
// Merged prep: pad raw features to 16 f16/row AND fold input-projection +
// layer-1 weights into padded fused matrices (one launch).
__global__ __launch_bounds__(256) void prep(
        const float* __restrict__ x_site, const float* __restrict__ x_vendor,
        unsigned short* __restrict__ xsp, unsigned short* __restrict__ xvp,
        const float* __restrict__ Wsi, const float* __restrict__ bsi,
        const float* __restrict__ Wvi, const float* __restrict__ bvi,
        const float* __restrict__ Wl1sv, const float* __restrict__ Wr1sv,
        const float* __restrict__ Wl1vs, const float* __restrict__ Wr1vs,
        float* __restrict__ fused) {
    long long t = (long long)blockIdx.x * 256 + threadIdx.x;
    if (t < (long long)N_SITE * 16) {
        int i = (int)(t >> 4), k = (int)(t & 15);
        xsp[t] = f2h(k < SITE_IN ? x_site[i * SITE_IN + k] : 0.f);
        return;
    }
    t -= (long long)N_SITE * 16;
    if (t < (long long)N_VENDOR * 16) {
        int i = (int)(t >> 4), k = (int)(t & 15);
        xvp[t] = f2h(k < VENDOR_IN ? x_vendor[i * VENDOR_IN + k] : 0.f);
        return;
    }
    t -= (long long)N_VENDOR * 16;
    int idx = (int)t;
    if (idx < 4096) {                       // matrices, m = 0..3 (16x64 each)
        int m = idx >> 10, rem = idx & 1023, r = rem >> 6, c = rem & 63;
        int K = (m == 0 || m == 3) ? SITE_IN : VENDOR_IN;
        const float* A = (m == 0 || m == 3) ? Wsi : Wvi;
        const float* B = (m == 0) ? Wl1sv : (m == 1) ? Wl1vs : (m == 2) ? Wr1sv : Wr1vs;
        float s = 0.f;
        if (r < K)
            for (int j = 0; j < 64; ++j) s = fmaf(A[r * 64 + j], B[j * 64 + c], s);
        fused[idx] = s;
    } else if (idx < 4352) {                // bias vectors
        int m = (idx - 4096) >> 6, c = idx & 63;
        const float* a = (m == 0 || m == 3) ? bsi : bvi;
        const float* B = (m == 0) ? Wl1sv : (m == 1) ? Wl1vs : (m == 2) ? Wr1sv : Wr1vs;
        float s = 0.f;
        for (int j = 0; j < 64; ++j) s = fmaf(a[j], B[j * 64 + c], s);
        fused[idx] = s;
    }
}

// ---------------------------------------------------------------------------
// Build K1 (single pass over edges, chunk re-read is L2-hot): per-block LDS
// bucket histogram -> ONE global atomicAdd per (block,bucket) reserves a
// range in the fixed-capacity padded pairs region -> scatter both directions.
// site pair:   (site&127)<<25 | vendor   (vendor < 2^15)
// vendor pair: (vendor&63)<<26 | site    (site < 2^17)
__global__ __launch_bounds__(256) void scatter_res(
        const int* __restrict__ src, const int* __restrict__ dst,
        int* __restrict__ gcur,
        unsigned* __restrict__ pairs_s, unsigned* __restrict__ pairs_v) {
    __shared__ int hs[NBUK_S];
    __shared__ int hv[NBUK_V];
    int blk = blockIdx.x, tid = threadIdx.x;
    for (int i = tid; i < NBUK_S; i += 256) hs[i] = 0;
    for (int i = tid; i < NBUK_V; i += 256) hv[i] = 0;
    __syncthreads();
    int lo = blk * EPB;
    for (int e = lo + tid; e < lo + EPB; e += 256) {
        atomicAdd(&hs[src[e] >> SHIFT_S], 1);
        atomicAdd(&hv[dst[e] >> SHIFT_V], 1);
    }
    __syncthreads();
    // reserve ranges; store within-bucket base back into the LDS slot
    for (int i = tid; i < NBUK_S; i += 256) {
        int c = hs[i];
        hs[i] = c ? atomicAdd(&gcur[i], c) : 0;
    }
    for (int i = tid; i < NBUK_V; i += 256) {
        int c = hv[i];
        hv[i] = c ? atomicAdd(&gcur[NBUK_S + i], c) : 0;
    }
    __syncthreads();
    for (int e = lo + tid; e < lo + EPB; e += 256) {
        int s = src[e], d = dst[e];
        int bs = s >> SHIFT_S;
        int ps = atomicAdd(&hs[bs], 1);
        if (ps < CAP_S)
            pairs_s[(long long)bs * CAP_S + ps] =
                ((unsigned)(s & 127) << 25) | (unsigned)d;
        int bv = d >> SHIFT_V;
        int pv = atomicAdd(&hv[bv], 1);
        if (pv < CAP_V)
            pairs_v[(long long)bv * CAP_V + pv] =
                ((unsigned)(d & 63) << 26) | (unsigned)s;
    }
}

// Build K2: per-bucket counting sort for BOTH directions (grid-split), in the
// padded layout. Emits nstart[] (global padded index) and ndeg[] per node.
__global__ __launch_bounds__(256) void stage2both(
        const unsigned* __restrict__ pairs_s, const unsigned* __restrict__ pairs_v,
        const int* __restrict__ gcur,
        int* __restrict__ nstart_s, int* __restrict__ ndeg_s,
        int* __restrict__ nstart_v, int* __restrict__ ndeg_v,
        unsigned short* __restrict__ adj_s16, int* __restrict__ adj_v) {
    int b = blockIdx.x, tid = threadIdx.x;
    bool site = (b < NBUK_S);
    const unsigned* pairs; int *nst, *ndg;
    int BW, nnode, shloc, lo_node, cnt;
    long long p0;
    if (site) {
        pairs = pairs_s; nst = nstart_s; ndg = ndeg_s;
        BW = 128; nnode = N_SITE; shloc = 25; lo_node = b << SHIFT_S;
        p0 = (long long)b * CAP_S;
        cnt = min(gcur[b], CAP_S);
    } else {
        b -= NBUK_S;
        pairs = pairs_v; nst = nstart_v; ndg = ndeg_v;
        BW = 64; nnode = N_VENDOR; shloc = 26; lo_node = b << SHIFT_V;
        p0 = (long long)b * CAP_V;
        cnt = min(gcur[NBUK_S + b], CAP_V);
    }
    long long p1 = p0 + cnt;
    __shared__ int deg[128];
    __shared__ int cur[128];
    __shared__ int sc[256];
    if (tid < BW) deg[tid] = 0;
    __syncthreads();
    for (long long e = p0 + tid; e < p1; e += 256)
        atomicAdd(&deg[(int)(pairs[e] >> shloc)], 1);
    __syncthreads();
    int d = (tid < BW) ? deg[tid] : 0;
    sc[tid] = d;
    __syncthreads();
    for (int st = 1; st < 256; st <<= 1) {
        int x = (tid >= st) ? sc[tid - st] : 0; __syncthreads();
        sc[tid] += x; __syncthreads();
    }
    int excl = sc[tid] - d;
    if (tid < BW) {
        int node = lo_node + tid;
        if (node < nnode) {
            nst[node] = (int)(p0 + excl);
            ndg[node] = d;
        }
        cur[tid] = (int)(p0 + excl);
    }
    __syncthreads();
    if (site) {
        for (long long e = p0 + tid; e < p1; e += 256) {
            unsigned p = pairs[e];
            int pos = atomicAdd(&cur[(int)(p >> 25)], 1);
            adj_s16[pos] = (unsigned short)p;           // vendor id < 2^15
        }
    } else {
        for (long long e = p0 + tid; e < p1; e += 256) {
            unsigned p = pairs[e];
            int pos = atomicAdd(&cur[(int)(p >> 26)], 1);
            adj_v[pos] = (int)(p & 0x3FFFFFFu);         // site id < 2^17
        }
    }
}

// ---------------------------------------------------------------------------
// Layer-1 gather helper: 16 lanes per node; f16 rows, fdot2 accumulate.
template<typename IdxT>
__device__ __forceinline__ void gather1x(const unsigned short* __restrict__ fp,
                                         const IdxT* __restrict__ adj,
                                         int lo, int hi, int l16, float* s) {
    for (int j = lo + l16; j < hi; j += 16) {
        const unsigned short* row = fp + (long long)adj[j] * 16;
        uint4 q0 = *(const uint4*)row;
        unsigned u4 = *(const unsigned*)(row + 8);
        acc2(s[0], s[1], q0.x);
        acc2(s[2], s[3], q0.y);
        acc2(s[4], s[5], q0.z);
        acc2(s[6], s[7], q0.w);
        acc2(s[8], s[9], u4);
    }
}

// Fused layer-1 + layer-2 projection. Block = 256 threads = 16 nodes
// (16 lanes/node). Stage B: gather padded f16 neighbor rows, 4-step
// butterfly, fused mean-project + fp32 self-project + relu -> x1 (f16 pairs)
// into LDS. Stage C: [y|z] = x1 @ [Wl2|Wr2] via v_dot2_f32_f16 from f16-pair
// LDS; y -> f16 table (64B rows), z -> fp32 directly into d_out.
__global__ __launch_bounds__(256) void gc1fused(
        const unsigned short* __restrict__ xsp, const unsigned short* __restrict__ xvp,
        const float* __restrict__ xs_raw, const float* __restrict__ xv_raw,
        const int* __restrict__ nstart_s, const int* __restrict__ ndeg_s,
        const unsigned short* __restrict__ adj_s16,
        const int* __restrict__ nstart_v, const int* __restrict__ ndeg_v,
        const int* __restrict__ adj_v,
        const float* __restrict__ fused,
        const float* __restrict__ bl1vs, const float* __restrict__ bl1sv,
        const float* __restrict__ Wl2sv, const float* __restrict__ Wr2vs,
        const float* __restrict__ Wl2vs, const float* __restrict__ Wr2sv,
        unsigned short* __restrict__ ys16, unsigned short* __restrict__ yv16,
        float* __restrict__ out) {
    __shared__ unsigned sWp[32 * 64];   // [kk][c]: f16 pair (W[2kk][c], W[2kk+1][c])
    __shared__ unsigned sXp[16][34];    // [node][kk]: f16 pair (x[2kk], x[2kk+1])
    int b = blockIdx.x, tid = threadIdx.x;
    bool site = (b < NS_BLK);
    const float *fsraw, *M, *V, *BL, *R, *RV, *Wl, *Wr;
    const int *nst, *ndg;
    unsigned short* Y; float* Z;
    int nodebase, n, kx;
    if (site) {          // site node: aggregate vendor feats, self = site feats
        nodebase = b * 16; n = N_SITE; kx = SITE_IN;
        fsraw = xs_raw; nst = nstart_s; ndg = ndeg_s;
        M = fused + F_M1VS; V = fused + F_V1VS; BL = bl1vs;
        R = fused + F_R1VS; RV = fused + F_r1VS;
        Wl = Wl2sv; Wr = Wr2vs; Y = ys16; Z = out;
    } else {             // vendor node
        nodebase = (b - NS_BLK) * 16; n = N_VENDOR; kx = VENDOR_IN;
        fsraw = xv_raw; nst = nstart_v; ndg = ndeg_v;
        M = fused + F_M1SV; V = fused + F_V1SV; BL = bl1sv;
        R = fused + F_R1SV; RV = fused + F_r1SV;
        Wl = Wl2vs; Wr = Wr2sv; Y = yv16;
        Z = out + (long long)N_SITE * OUT;
    }
    // stage W into LDS as f16 k-pairs
    for (int i = tid; i < 2048; i += 256) {
        int kk = i >> 6, c = i & 63;
        int k0 = kk * 2, k1 = k0 + 1;
        float w0 = (c < 32) ? Wl[k0 * 32 + c] : Wr[k0 * 32 + (c - 32)];
        float w1 = (c < 32) ? Wl[k1 * 32 + c] : Wr[k1 * 32 + (c - 32)];
        sWp[i] = (unsigned)f2h(w0) | ((unsigned)f2h(w1) << 16);
    }
    // ---- Stage B: layer-1 for this thread's node (16 lanes/node) ----
    int l16 = tid & 15, nib = tid >> 4;
    int w = nodebase + nib;
    int c0 = l16 * 4;
    if (w < n) {
        int lo = nst[w], deg = ndg[w], hi = lo + deg;
        float s[10];
        #pragma unroll
        for (int k = 0; k < 10; ++k) s[k] = 0.f;
        if (site) gather1x(xvp, adj_s16, lo, hi, l16, s);
        else      gather1x(xsp, adj_v,   lo, hi, l16, s);
        #pragma unroll
        for (int k = 0; k < 10; ++k) {
            s[k] += __shfl_xor(s[k], 1, 64);
            s[k] += __shfl_xor(s[k], 2, 64);
            s[k] += __shfl_xor(s[k], 4, 64);
            s[k] += __shfl_xor(s[k], 8, 64);
        }
        float inv = 1.0f / (float)max(deg, 1);
        float4 acc = *(const float4*)(BL + c0);
        float4 rv4 = *(const float4*)(RV + c0);
        acc.x += rv4.x; acc.y += rv4.y; acc.z += rv4.z; acc.w += rv4.w;
        if (deg > 0) {
            float4 v4 = *(const float4*)(V + c0);
            acc.x += v4.x; acc.y += v4.y; acc.z += v4.z; acc.w += v4.w;
        }
        #pragma unroll
        for (int k = 0; k < 10; ++k) {
            float m = s[k] * inv;
            float4 m4 = *(const float4*)(M + k * 64 + c0);
            acc.x = fmaf(m, m4.x, acc.x);
            acc.y = fmaf(m, m4.y, acc.y);
            acc.z = fmaf(m, m4.z, acc.z);
            acc.w = fmaf(m, m4.w, acc.w);
        }
        const float* xr = fsraw + (long long)w * kx;   // broadcast fp32 self row
        for (int k = 0; k < kx; ++k) {
            float xv = xr[k];
            float4 r4 = *(const float4*)(R + k * 64 + c0);
            acc.x = fmaf(xv, r4.x, acc.x);
            acc.y = fmaf(xv, r4.y, acc.y);
            acc.z = fmaf(xv, r4.z, acc.z);
            acc.w = fmaf(xv, r4.w, acc.w);
        }
        unsigned plo = (unsigned)f2h(fmaxf(acc.x, 0.f)) |
                       ((unsigned)f2h(fmaxf(acc.y, 0.f)) << 16);
        unsigned phi = (unsigned)f2h(fmaxf(acc.z, 0.f)) |
                       ((unsigned)f2h(fmaxf(acc.w, 0.f)) << 16);
        *(uint2*)&sXp[nib][l16 * 2] = make_uint2(plo, phi);
    }
    __syncthreads();
    // ---- Stage C: [y|z] = x1 @ [Wl|Wr] via dot2 (32 k-pair iters) ----
    int n2 = tid >> 4, q = tid & 15;   // node, col-group (cols 4q..4q+3)
    int node = nodebase + n2;
    float4 acc = {0.f, 0.f, 0.f, 0.f};
    const unsigned* xrow = sXp[n2];
    #pragma unroll 8
    for (int kk = 0; kk < 32; ++kk) {
        unsigned xp = xrow[kk];                       // LDS broadcast / 16 thr
        uint4 wp = *(const uint4*)(sWp + kk * 64 + q * 4);
        acc.x = ddot2(xp, wp.x, acc.x);
        acc.y = ddot2(xp, wp.y, acc.y);
        acc.z = ddot2(xp, wp.z, acc.z);
        acc.w = ddot2(xp, wp.w, acc.w);
    }
    if (node < n) {
        if (q < 8) {
            unsigned p01 = (unsigned)f2h(acc.x) | ((unsigned)f2h(acc.y) << 16);
            unsigned p23 = (unsigned)f2h(acc.z) | ((unsigned)f2h(acc.w) << 16);
            *(uint2*)(Y + (long long)node * 32 + q * 4) = make_uint2(p01, p23);
        } else {
            *(float4*)(Z + (long long)node * 32 + (q - 8) * 4) = acc;
        }
    }
}

// ---------------------------------------------------------------------------
// Layer-2 gather helper: 8 edge-groups x 8 lanes; each lane covers 4 f16
// cols via one uint2 per edge; 4-deep unroll for MLP on the latency-bound
// vendor-direction (m ~ deg/8 ~ 20 sequential loads otherwise).
template<typename IdxT>
__device__ __forceinline__ void gather2(const unsigned short* __restrict__ y,
                                        const IdxT* __restrict__ adj,
                                        int lo, int deg, int g, int q,
                                        float& s0, float& s1, float& s2, float& s3) {
    int m = (deg > g) ? ((deg - g + 7) >> 3) : 0;
    const IdxT* ap = adj + lo + g;
    int t = 0;
    for (; t + 4 <= m; t += 4) {
        long long a0 = (long long)ap[8 * t];
        long long a1 = (long long)ap[8 * t + 8];
        long long a2 = (long long)ap[8 * t + 16];
        long long a3 = (long long)ap[8 * t + 24];
        uint2 u0 = *(const uint2*)(y + a0 * 32 + 4 * q);
        uint2 u1 = *(const uint2*)(y + a1 * 32 + 4 * q);
        uint2 u2 = *(const uint2*)(y + a2 * 32 + 4 * q);
        uint2 u3 = *(const uint2*)(y + a3 * 32 + 4 * q);
        acc2(s0, s1, u0.x); acc2(s2, s3, u0.y);
        acc2(s0, s1, u1.x); acc2(s2, s3, u1.y);
        acc2(s0, s1, u2.x); acc2(s2, s3, u2.y);
        acc2(s0, s1, u3.x); acc2(s2, s3, u3.y);
    }
    for (; t < m; ++t) {
        long long a0 = (long long)ap[8 * t];
        uint2 u0 = *(const uint2*)(y + a0 * 32 + 4 * q);
        acc2(s0, s1, u0.x); acc2(s2, s3, u0.y);
    }
}

// Merged layer-2 combine: out = relu(gather_mean(f16 y) + b + z) where z was
// pre-written into d_out by gc1fused. One wave per node.
__global__ __launch_bounds__(256) void gc2all(
        const unsigned short* __restrict__ ys16, const unsigned short* __restrict__ yv16,
        const int* __restrict__ nstart_s, const int* __restrict__ ndeg_s,
        const unsigned short* __restrict__ adj_s16,
        const int* __restrict__ nstart_v, const int* __restrict__ ndeg_v,
        const int* __restrict__ adj_v,
        const float* __restrict__ bl2vs, const float* __restrict__ bl2sv,
        float* __restrict__ out) {
    int b = blockIdx.x;
    bool site = (b < SB1);
    const float* bias; const int *nst, *ndg; float* o; int w, n;
    if (site) {          // site outputs gather vendor pre-projections
        w = b * 4 + (threadIdx.x >> 6); n = N_SITE;
        nst = nstart_s; ndg = ndeg_s; bias = bl2vs; o = out;
    } else {
        w = (b - SB1) * 4 + (threadIdx.x >> 6); n = N_VENDOR;
        nst = nstart_v; ndg = ndeg_v; bias = bl2sv;
        o = out + (long long)N_SITE * OUT;
    }
    if (w >= n) return;
    int lane = threadIdx.x & 63, g = lane >> 3, q = lane & 7;
    int lo = nst[w], deg = ndg[w];
    float s0 = 0.f, s1 = 0.f, s2 = 0.f, s3 = 0.f;
    if (site) gather2(yv16, adj_s16, lo, deg, g, q, s0, s1, s2, s3);
    else      gather2(ys16, adj_v,   lo, deg, g, q, s0, s1, s2, s3);
    #pragma unroll
    for (int m = 8; m <= 32; m <<= 1) {
        s0 += __shfl_xor(s0, m, 64);
        s1 += __shfl_xor(s1, m, 64);
        s2 += __shfl_xor(s2, m, 64);
        s3 += __shfl_xor(s3, m, 64);
    }
    if (g == 0) {
        float inv = 1.0f / (float)max(deg, 1);
        float4 bz = *(const float4*)(bias + 4 * q);
        long long oi = (long long)w * 32 + 4 * q;
        float4 z = *(const float4*)(o + oi);
        float4 r;
        r.x = fmaxf(fmaf(s0, inv, bz.x + z.x), 0.f);
        r.y = fmaxf(fmaf(s1, inv, bz.y + z.y), 0.f);
        r.z = fmaxf(fmaf(s2, inv, bz.z + z.z), 0.f);
        r.w = fmaxf(fmaf(s3, inv, bz.w + z.w), 0.f);
        *(float4*)(o + oi) = r;
    }
}

// ---------------------------------------------------------------------------
extern "C" void kernel_launch(void* const* d_in, const int* in_sizes, int n_in,
                              void* d_out, int out_size, void* d_ws, size_t ws_size,
                              hipStream_t stream) {
    const float* x_site      = (const float*)d_in[0];
    const float* x_vendor    = (const float*)d_in[1];
    const int*   src         = (const int*)d_in[2];
    const int*   dst         = (const int*)d_in[3];
    const float* W_site_in   = (const float*)d_in[4];
    const float* b_site_in   = (const float*)d_in[5];
    const float* W_vendor_in = (const float*)d_in[6];
    const float* b_vendor_in = (const float*)d_in[7];
    const float* Wl1sv = (const float*)d_in[8];
    const float* bl1sv = (const float*)d_in[9];
    const float* Wr1sv = (const float*)d_in[10];
    const float* Wl1vs = (const float*)d_in[11];
    const float* bl1vs = (const float*)d_in[12];
    const float* Wr1vs = (const float*)d_in[13];
    const float* Wl2sv = (const float*)d_in[14];
    const float* bl2sv = (const float*)d_in[15];
    const float* Wr2sv = (const float*)d_in[16];
    const float* Wl2vs = (const float*)d_in[17];
    const float* bl2vs = (const float*)d_in[18];
    const float* Wr2vs = (const float*)d_in[19];

    // Guard: never write past harness scratch (overrun can kill the container).
    if (ws_size < (size_t)WS_WORDS * 4) return;

    int*   wi  = (int*)d_ws;
    float* wf  = (float*)d_ws;
    float* out = (float*)d_out;

    int* nstart_s = wi + I_NSTART_S;
    int* ndeg_s   = wi + I_NDEG_S;
    int* nstart_v = wi + I_NSTART_V;
    int* ndeg_v   = wi + I_NDEG_V;
    int* gcur     = wi + I_GCUR;
    int* adj_v    = wi + I_ADJ_V;
    unsigned short* adj_s16 = (unsigned short*)(wi + I_ADJ_S);
    unsigned* pairs_s = (unsigned*)(wi + A_PAIRS_S);
    unsigned* pairs_v = (unsigned*)(wi + A_PAIRS_V);
    unsigned short* ys16 = (unsigned short*)(wf + F_Y16);
    unsigned short* yv16 = ys16 + (long long)N_SITE * 32;
    unsigned short* xsp  = (unsigned short*)(wf + F_PAD);
    unsigned short* xvp  = xsp + (long long)N_SITE * 16;
    float* fused = wf + F_FUSED;

    // zero bucket cursors (ws not re-poisoned between replays; zero every call)
    hipMemsetAsync(gcur, 0, (size_t)(NBUK_S + NBUK_V) * sizeof(int), stream);

    // merged pad + weight-fold
    prep<<<(PADTOT + 4352 + 255) / 256, 256, 0, stream>>>(
        x_site, x_vendor, xsp, xvp,
        W_site_in, b_site_in, W_vendor_in, b_vendor_in,
        Wl1sv, Wr1sv, Wl1vs, Wr1vs, fused);

    // --- CSR build: fixed-capacity buckets, one edge pass + in-bucket sort ---
    scatter_res<<<NBLK, 256, 0, stream>>>(src, dst, gcur, pairs_s, pairs_v);
    stage2both<<<NBUK_S + NBUK_V, 256, 0, stream>>>(pairs_s, pairs_v, gcur,
                                                    nstart_s, ndeg_s,
                                                    nstart_v, ndeg_v,
                                                    adj_s16, adj_v);

    // --- layer 1 + layer-2 projection, fully fused (both directions) ---
    gc1fused<<<NS_BLK + NV_BLK, 256, 0, stream>>>(
        xsp, xvp, x_site, x_vendor,
        nstart_s, ndeg_s, adj_s16, nstart_v, ndeg_v, adj_v,
        fused, bl1vs, bl1sv, Wl2sv, Wr2vs, Wl2vs, Wr2sv,
        ys16, yv16, out);

    // --- layer 2: merged gather+mean+bias+self+relu ---
    gc2all<<<SB1 + VB1, 256, 0, stream>>>(ys16, yv16,
                                          nstart_s, ndeg_s, adj_s16,
                                          nstart_v, ndeg_v, adj_v,
                                          bl2vs, bl2sv, out);

    (void)in_sizes; (void)n_in; (void)out_size;
}

// Round 15
// 292.024 us; speedup vs baseline: 1.2124x; 1.1165x over previous
//
#include <hip/hip_runtime.h>

// Problem constants
constexpr int N_SITE    = 100000;
constexpr int N_VENDOR  = 20000;
constexpr int NE        = 3200000;
constexpr int SITE_IN   = 10;
constexpr int VENDOR_IN = 9;
constexpr int HID       = 64;
constexpr int OUT       = 32;

// Radix-build parameters: fixed-capacity buckets. NBLK=256 (12500 edges per
// chunk) so each (block,bucket) write run is ~16 edges = 64B = one full cache
// line in the site direction (vendor: ~40 edges = 160B) -> no partial-line
// write amplification (round-14: NBLK=1024 gave 16B runs -> 7.4x WRITE_SIZE).
constexpr int NBLK    = 256;             // scatter grid (each block = one chunk)
constexpr int EPB     = NE / NBLK;       // 12500 edges per block
constexpr int SHIFT_S = 7;               // 128 sites per bucket
constexpr int NBUK_S  = (N_SITE + 127) / 128;    // 782
constexpr int CAP_S   = 5120;            // mean 4096, sigma 64 -> +16 sigma
constexpr int SHIFT_V = 6;               // 64 vendors per bucket
constexpr int NBUK_V  = (N_VENDOR + 63) / 64;    // 313
constexpr int CAP_V   = 12288;           // mean 10240, sigma 101 -> +20 sigma

// Launch geometry
constexpr int SB1  = (N_SITE + 3) / 4;           // 25000 (gc2 site blocks)
constexpr int VB1  = (N_VENDOR + 3) / 4;         // 5000
constexpr int NS_BLK = (N_SITE + 15) / 16;       // 6250 (gc1fused site blocks)
constexpr int NV_BLK = (N_VENDOR + 15) / 16;     // 1250
constexpr int PADTOT = 16 * (N_SITE + N_VENDOR); // padded f16 feature elems

// ---------------------------------------------------------------------------
// Workspace layout (4-byte words).
constexpr long long I_NSTART_S = 0;                               // [N_SITE]
constexpr long long I_NDEG_S   = I_NSTART_S + N_SITE;             // [N_SITE]
constexpr long long I_NSTART_V = I_NDEG_S + N_SITE;               // [N_VENDOR]
constexpr long long I_NDEG_V   = I_NSTART_V + N_VENDOR;           // [N_VENDOR]
constexpr long long I_GCUR     = I_NDEG_V + N_VENDOR;             // [NBUK_S+NBUK_V] zero/call
constexpr long long I_ADJ_V    = (I_GCUR + NBUK_S + NBUK_V + 3) & ~3LL; // [NBUK_V*CAP_V] int
constexpr long long I_ADJ_S    = I_ADJ_V + (long long)NBUK_V * CAP_V;   // u16[NBUK_S*CAP_S]
constexpr long long INT_END    = (I_ADJ_S + (long long)NBUK_S * CAP_S / 2 + 3) & ~3LL;
constexpr long long A_PAIRS_S  = INT_END;                         // [NBUK_S*CAP_S] u32
constexpr long long A_PAIRS_V  = A_PAIRS_S + (long long)NBUK_S * CAP_S;
constexpr long long BUILD_END  = A_PAIRS_V + (long long)NBUK_V * CAP_V;
// f16 y tables (gc1fused -> gc2all), 64B rows (32 f16). Written after
// stage2both consumed pairs -> placed after BUILD_END (no aliasing).
constexpr long long F_Y16    = (BUILD_END + 3) & ~3LL;
constexpr long long F_PAD    = F_Y16 + (long long)(N_SITE + N_VENDOR) * 16;
constexpr long long F_FUSED  = F_PAD + (long long)(N_SITE + N_VENDOR) * 8; // [4352]
constexpr long long WS_WORDS = F_FUSED + 4352;                   // ~67.4 MB

// fused sub-offsets (layer-1 matrices padded to 16 rows; pad rows are ZERO)
constexpr int F_M1SV = 0;      // 16x64  W_site_in@Wl1sv   (rows 10..15 = 0)
constexpr int F_M1VS = 1024;   // 16x64  W_vendor_in@Wl1vs (rows 9..15 = 0)
constexpr int F_R1SV = 2048;   // 16x64  W_vendor_in@Wr1sv
constexpr int F_R1VS = 3072;   // 16x64  W_site_in@Wr1vs
constexpr int F_V1SV = 4096;   // 64     b_site_in@Wl1sv
constexpr int F_V1VS = 4160;   // 64     b_vendor_in@Wl1vs
constexpr int F_r1SV = 4224;   // 64     b_vendor_in@Wr1sv
constexpr int F_r1VS = 4288;   // 64     b_site_in@Wr1vs

// ---------------------------------------------------------------------------
// f16 helpers. v_dot2_f32_f16 when available; cvt+fma fallback.
typedef _Float16 h2_t __attribute__((ext_vector_type(2)));
__device__ __forceinline__ h2_t as_h2(unsigned u) {
    union { unsigned u; h2_t h; } c; c.u = u; return c.h;
}
__device__ __forceinline__ unsigned short f2h(float f) {
    union { _Float16 h; unsigned short u; } c; c.h = (_Float16)f; return c.u;
}
#if defined(__has_builtin)
#if __has_builtin(__builtin_amdgcn_fdot2)
#define HAVE_FDOT2 1
#endif
#endif
__device__ __forceinline__ void acc2(float& slo, float& shi, unsigned u) {
#ifdef HAVE_FDOT2
    h2_t sel_lo = {(_Float16)1.0f, (_Float16)0.0f};
    h2_t sel_hi = {(_Float16)0.0f, (_Float16)1.0f};
    slo = __builtin_amdgcn_fdot2(as_h2(u), sel_lo, slo, false);
    shi = __builtin_amdgcn_fdot2(as_h2(u), sel_hi, shi, false);
#else
    h2_t h = as_h2(u);
    slo += (float)h.x; shi += (float)h.y;
#endif
}
__device__ __forceinline__ float ddot2(unsigned a, unsigned b, float c) {
#ifdef HAVE_FDOT2
    return __builtin_amdgcn_fdot2(as_h2(a), as_h2(b), c, false);
#else
    h2_t ha = as_h2(a), hb = as_h2(b);
    return c + (float)ha.x * (float)hb.x + (float)ha.y * (float)hb.y;
#endif
}

// ---------------------------------------------------------------------------
// Merged prep: pad raw features to 16 f16/row AND fold input-projection +
// layer-1 weights into padded fused matrices (one launch).
__global__ __launch_bounds__(256) void prep(
        const float* __restrict__ x_site, const float* __restrict__ x_vendor,
        unsigned short* __restrict__ xsp, unsigned short* __restrict__ xvp,
        const float* __restrict__ Wsi, const float* __restrict__ bsi,
        const float* __restrict__ Wvi, const float* __restrict__ bvi,
        const float* __restrict__ Wl1sv, const float* __restrict__ Wr1sv,
        const float* __restrict__ Wl1vs, const float* __restrict__ Wr1vs,
        float* __restrict__ fused) {
    long long t = (long long)blockIdx.x * 256 + threadIdx.x;
    if (t < (long long)N_SITE * 16) {
        int i = (int)(t >> 4), k = (int)(t & 15);
        xsp[t] = f2h(k < SITE_IN ? x_site[i * SITE_IN + k] : 0.f);
        return;
    }
    t -= (long long)N_SITE * 16;
    if (t < (long long)N_VENDOR * 16) {
        int i = (int)(t >> 4), k = (int)(t & 15);
        xvp[t] = f2h(k < VENDOR_IN ? x_vendor[i * VENDOR_IN + k] : 0.f);
        return;
    }
    t -= (long long)N_VENDOR * 16;
    int idx = (int)t;
    if (idx < 4096) {                       // matrices, m = 0..3 (16x64 each)
        int m = idx >> 10, rem = idx & 1023, r = rem >> 6, c = rem & 63;
        int K = (m == 0 || m == 3) ? SITE_IN : VENDOR_IN;
        const float* A = (m == 0 || m == 3) ? Wsi : Wvi;
        const float* B = (m == 0) ? Wl1sv : (m == 1) ? Wl1vs : (m == 2) ? Wr1sv : Wr1vs;
        float s = 0.f;
        if (r < K)
            for (int j = 0; j < 64; ++j) s = fmaf(A[r * 64 + j], B[j * 64 + c], s);
        fused[idx] = s;
    } else if (idx < 4352) {                // bias vectors
        int m = (idx - 4096) >> 6, c = idx & 63;
        const float* a = (m == 0 || m == 3) ? bsi : bvi;
        const float* B = (m == 0) ? Wl1sv : (m == 1) ? Wl1vs : (m == 2) ? Wr1sv : Wr1vs;
        float s = 0.f;
        for (int j = 0; j < 64; ++j) s = fmaf(a[j], B[j * 64 + c], s);
        fused[idx] = s;
    }
}

// ---------------------------------------------------------------------------
// Build K1 (single pass over edges, chunk re-read is L2-hot): per-block LDS
// bucket histogram -> ONE global atomicAdd per (block,bucket) reserves a
// range in the fixed-capacity padded pairs region -> scatter both directions
// in full-cache-line runs.
// site pair:   (site&127)<<25 | vendor   (vendor < 2^15)
// vendor pair: (vendor&63)<<26 | site    (site < 2^17)
__global__ __launch_bounds__(256) void scatter_res(
        const int* __restrict__ src, const int* __restrict__ dst,
        int* __restrict__ gcur,
        unsigned* __restrict__ pairs_s, unsigned* __restrict__ pairs_v) {
    __shared__ int hs[NBUK_S];
    __shared__ int hv[NBUK_V];
    int blk = blockIdx.x, tid = threadIdx.x;
    for (int i = tid; i < NBUK_S; i += 256) hs[i] = 0;
    for (int i = tid; i < NBUK_V; i += 256) hv[i] = 0;
    __syncthreads();
    int lo = blk * EPB;
    for (int e = lo + tid; e < lo + EPB; e += 256) {
        atomicAdd(&hs[src[e] >> SHIFT_S], 1);
        atomicAdd(&hv[dst[e] >> SHIFT_V], 1);
    }
    __syncthreads();
    // reserve ranges; store within-bucket base back into the LDS slot
    for (int i = tid; i < NBUK_S; i += 256) {
        int c = hs[i];
        hs[i] = c ? atomicAdd(&gcur[i], c) : 0;
    }
    for (int i = tid; i < NBUK_V; i += 256) {
        int c = hv[i];
        hv[i] = c ? atomicAdd(&gcur[NBUK_S + i], c) : 0;
    }
    __syncthreads();
    for (int e = lo + tid; e < lo + EPB; e += 256) {
        int s = src[e], d = dst[e];
        int bs = s >> SHIFT_S;
        int ps = atomicAdd(&hs[bs], 1);
        if (ps < CAP_S)
            pairs_s[(long long)bs * CAP_S + ps] =
                ((unsigned)(s & 127) << 25) | (unsigned)d;
        int bv = d >> SHIFT_V;
        int pv = atomicAdd(&hv[bv], 1);
        if (pv < CAP_V)
            pairs_v[(long long)bv * CAP_V + pv] =
                ((unsigned)(d & 63) << 26) | (unsigned)s;
    }
}

// Build K2: per-bucket counting sort for BOTH directions (grid-split), in the
// padded layout. Emits nstart[] (global padded index) and ndeg[] per node.
__global__ __launch_bounds__(256) void stage2both(
        const unsigned* __restrict__ pairs_s, const unsigned* __restrict__ pairs_v,
        const int* __restrict__ gcur,
        int* __restrict__ nstart_s, int* __restrict__ ndeg_s,
        int* __restrict__ nstart_v, int* __restrict__ ndeg_v,
        unsigned short* __restrict__ adj_s16, int* __restrict__ adj_v) {
    int b = blockIdx.x, tid = threadIdx.x;
    bool site = (b < NBUK_S);
    const unsigned* pairs; int *nst, *ndg;
    int BW, nnode, shloc, lo_node, cnt;
    long long p0;
    if (site) {
        pairs = pairs_s; nst = nstart_s; ndg = ndeg_s;
        BW = 128; nnode = N_SITE; shloc = 25; lo_node = b << SHIFT_S;
        p0 = (long long)b * CAP_S;
        cnt = min(gcur[b], CAP_S);
    } else {
        b -= NBUK_S;
        pairs = pairs_v; nst = nstart_v; ndg = ndeg_v;
        BW = 64; nnode = N_VENDOR; shloc = 26; lo_node = b << SHIFT_V;
        p0 = (long long)b * CAP_V;
        cnt = min(gcur[NBUK_S + b], CAP_V);
    }
    long long p1 = p0 + cnt;
    __shared__ int deg[128];
    __shared__ int cur[128];
    __shared__ int sc[256];
    if (tid < BW) deg[tid] = 0;
    __syncthreads();
    for (long long e = p0 + tid; e < p1; e += 256)
        atomicAdd(&deg[(int)(pairs[e] >> shloc)], 1);
    __syncthreads();
    int d = (tid < BW) ? deg[tid] : 0;
    sc[tid] = d;
    __syncthreads();
    for (int st = 1; st < 256; st <<= 1) {
        int x = (tid >= st) ? sc[tid - st] : 0; __syncthreads();
        sc[tid] += x; __syncthreads();
    }
    int excl = sc[tid] - d;
    if (tid < BW) {
        int node = lo_node + tid;
        if (node < nnode) {
            nst[node] = (int)(p0 + excl);
            ndg[node] = d;
        }
        cur[tid] = (int)(p0 + excl);
    }
    __syncthreads();
    if (site) {
        for (long long e = p0 + tid; e < p1; e += 256) {
            unsigned p = pairs[e];
            int pos = atomicAdd(&cur[(int)(p >> 25)], 1);
            adj_s16[pos] = (unsigned short)p;           // vendor id < 2^15
        }
    } else {
        for (long long e = p0 + tid; e < p1; e += 256) {
            unsigned p = pairs[e];
            int pos = atomicAdd(&cur[(int)(p >> 26)], 1);
            adj_v[pos] = (int)(p & 0x3FFFFFFu);         // site id < 2^17
        }
    }
}

// ---------------------------------------------------------------------------
// Layer-1 gather helper: 16 lanes per node; f16 rows, fdot2 accumulate.
template<typename IdxT>
__device__ __forceinline__ void gather1x(const unsigned short* __restrict__ fp,
                                         const IdxT* __restrict__ adj,
                                         int lo, int hi, int l16, float* s) {
    for (int j = lo + l16; j < hi; j += 16) {
        const unsigned short* row = fp + (long long)adj[j] * 16;
        uint4 q0 = *(const uint4*)row;
        unsigned u4 = *(const unsigned*)(row + 8);
        acc2(s[0], s[1], q0.x);
        acc2(s[2], s[3], q0.y);
        acc2(s[4], s[5], q0.z);
        acc2(s[6], s[7], q0.w);
        acc2(s[8], s[9], u4);
    }
}

// Fused layer-1 + layer-2 projection. Block = 256 threads = 16 nodes
// (16 lanes/node). Stage B: gather padded f16 neighbor rows, 4-step
// butterfly, fused mean-project + fp32 self-project + relu -> x1 (f16 pairs)
// into LDS. Stage C: [y|z] = x1 @ [Wl2|Wr2] via v_dot2_f32_f16 from f16-pair
// LDS; y -> f16 table (64B rows), z -> fp32 directly into d_out.
__global__ __launch_bounds__(256) void gc1fused(
        const unsigned short* __restrict__ xsp, const unsigned short* __restrict__ xvp,
        const float* __restrict__ xs_raw, const float* __restrict__ xv_raw,
        const int* __restrict__ nstart_s, const int* __restrict__ ndeg_s,
        const unsigned short* __restrict__ adj_s16,
        const int* __restrict__ nstart_v, const int* __restrict__ ndeg_v,
        const int* __restrict__ adj_v,
        const float* __restrict__ fused,
        const float* __restrict__ bl1vs, const float* __restrict__ bl1sv,
        const float* __restrict__ Wl2sv, const float* __restrict__ Wr2vs,
        const float* __restrict__ Wl2vs, const float* __restrict__ Wr2sv,
        unsigned short* __restrict__ ys16, unsigned short* __restrict__ yv16,
        float* __restrict__ out) {
    __shared__ unsigned sWp[32 * 64];   // [kk][c]: f16 pair (W[2kk][c], W[2kk+1][c])
    __shared__ unsigned sXp[16][34];    // [node][kk]: f16 pair (x[2kk], x[2kk+1])
    int b = blockIdx.x, tid = threadIdx.x;
    bool site = (b < NS_BLK);
    const float *fsraw, *M, *V, *BL, *R, *RV, *Wl, *Wr;
    const int *nst, *ndg;
    unsigned short* Y; float* Z;
    int nodebase, n, kx;
    if (site) {          // site node: aggregate vendor feats, self = site feats
        nodebase = b * 16; n = N_SITE; kx = SITE_IN;
        fsraw = xs_raw; nst = nstart_s; ndg = ndeg_s;
        M = fused + F_M1VS; V = fused + F_V1VS; BL = bl1vs;
        R = fused + F_R1VS; RV = fused + F_r1VS;
        Wl = Wl2sv; Wr = Wr2vs; Y = ys16; Z = out;
    } else {             // vendor node
        nodebase = (b - NS_BLK) * 16; n = N_VENDOR; kx = VENDOR_IN;
        fsraw = xv_raw; nst = nstart_v; ndg = ndeg_v;
        M = fused + F_M1SV; V = fused + F_V1SV; BL = bl1sv;
        R = fused + F_R1SV; RV = fused + F_r1SV;
        Wl = Wl2vs; Wr = Wr2sv; Y = yv16;
        Z = out + (long long)N_SITE * OUT;
    }
    // stage W into LDS as f16 k-pairs
    for (int i = tid; i < 2048; i += 256) {
        int kk = i >> 6, c = i & 63;
        int k0 = kk * 2, k1 = k0 + 1;
        float w0 = (c < 32) ? Wl[k0 * 32 + c] : Wr[k0 * 32 + (c - 32)];
        float w1 = (c < 32) ? Wl[k1 * 32 + c] : Wr[k1 * 32 + (c - 32)];
        sWp[i] = (unsigned)f2h(w0) | ((unsigned)f2h(w1) << 16);
    }
    // ---- Stage B: layer-1 for this thread's node (16 lanes/node) ----
    int l16 = tid & 15, nib = tid >> 4;
    int w = nodebase + nib;
    int c0 = l16 * 4;
    if (w < n) {
        int lo = nst[w], deg = ndg[w], hi = lo + deg;
        float s[10];
        #pragma unroll
        for (int k = 0; k < 10; ++k) s[k] = 0.f;
        if (site) gather1x(xvp, adj_s16, lo, hi, l16, s);
        else      gather1x(xsp, adj_v,   lo, hi, l16, s);
        #pragma unroll
        for (int k = 0; k < 10; ++k) {
            s[k] += __shfl_xor(s[k], 1, 64);
            s[k] += __shfl_xor(s[k], 2, 64);
            s[k] += __shfl_xor(s[k], 4, 64);
            s[k] += __shfl_xor(s[k], 8, 64);
        }
        float inv = 1.0f / (float)max(deg, 1);
        float4 acc = *(const float4*)(BL + c0);
        float4 rv4 = *(const float4*)(RV + c0);
        acc.x += rv4.x; acc.y += rv4.y; acc.z += rv4.z; acc.w += rv4.w;
        if (deg > 0) {
            float4 v4 = *(const float4*)(V + c0);
            acc.x += v4.x; acc.y += v4.y; acc.z += v4.z; acc.w += v4.w;
        }
        #pragma unroll
        for (int k = 0; k < 10; ++k) {
            float m = s[k] * inv;
            float4 m4 = *(const float4*)(M + k * 64 + c0);
            acc.x = fmaf(m, m4.x, acc.x);
            acc.y = fmaf(m, m4.y, acc.y);
            acc.z = fmaf(m, m4.z, acc.z);
            acc.w = fmaf(m, m4.w, acc.w);
        }
        const float* xr = fsraw + (long long)w * kx;   // broadcast fp32 self row
        for (int k = 0; k < kx; ++k) {
            float xv = xr[k];
            float4 r4 = *(const float4*)(R + k * 64 + c0);
            acc.x = fmaf(xv, r4.x, acc.x);
            acc.y = fmaf(xv, r4.y, acc.y);
            acc.z = fmaf(xv, r4.z, acc.z);
            acc.w = fmaf(xv, r4.w, acc.w);
        }
        unsigned plo = (unsigned)f2h(fmaxf(acc.x, 0.f)) |
                       ((unsigned)f2h(fmaxf(acc.y, 0.f)) << 16);
        unsigned phi = (unsigned)f2h(fmaxf(acc.z, 0.f)) |
                       ((unsigned)f2h(fmaxf(acc.w, 0.f)) << 16);
        *(uint2*)&sXp[nib][l16 * 2] = make_uint2(plo, phi);
    }
    __syncthreads();
    // ---- Stage C: [y|z] = x1 @ [Wl|Wr] via dot2 (32 k-pair iters) ----
    int n2 = tid >> 4, q = tid & 15;   // node, col-group (cols 4q..4q+3)
    int node = nodebase + n2;
    float4 acc = {0.f, 0.f, 0.f, 0.f};
    const unsigned* xrow = sXp[n2];
    #pragma unroll 8
    for (int kk = 0; kk < 32; ++kk) {
        unsigned xp = xrow[kk];                       // LDS broadcast / 16 thr
        uint4 wp = *(const uint4*)(sWp + kk * 64 + q * 4);
        acc.x = ddot2(xp, wp.x, acc.x);
        acc.y = ddot2(xp, wp.y, acc.y);
        acc.z = ddot2(xp, wp.z, acc.z);
        acc.w = ddot2(xp, wp.w, acc.w);
    }
    if (node < n) {
        if (q < 8) {
            unsigned p01 = (unsigned)f2h(acc.x) | ((unsigned)f2h(acc.y) << 16);
            unsigned p23 = (unsigned)f2h(acc.z) | ((unsigned)f2h(acc.w) << 16);
            *(uint2*)(Y + (long long)node * 32 + q * 4) = make_uint2(p01, p23);
        } else {
            *(float4*)(Z + (long long)node * 32 + (q - 8) * 4) = acc;
        }
    }
}

// ---------------------------------------------------------------------------
// Layer-2 gather helper: 8 edge-groups x 8 lanes; each lane covers 4 f16
// cols via one uint2 per edge; 4-deep unroll for MLP.
template<typename IdxT>
__device__ __forceinline__ void gather2(const unsigned short* __restrict__ y,
                                        const IdxT* __restrict__ adj,
                                        int lo, int deg, int g, int q,
                                        float& s0, float& s1, float& s2, float& s3) {
    int m = (deg > g) ? ((deg - g + 7) >> 3) : 0;
    const IdxT* ap = adj + lo + g;
    int t = 0;
    for (; t + 4 <= m; t += 4) {
        long long a0 = (long long)ap[8 * t];
        long long a1 = (long long)ap[8 * t + 8];
        long long a2 = (long long)ap[8 * t + 16];
        long long a3 = (long long)ap[8 * t + 24];
        uint2 u0 = *(const uint2*)(y + a0 * 32 + 4 * q);
        uint2 u1 = *(const uint2*)(y + a1 * 32 + 4 * q);
        uint2 u2 = *(const uint2*)(y + a2 * 32 + 4 * q);
        uint2 u3 = *(const uint2*)(y + a3 * 32 + 4 * q);
        acc2(s0, s1, u0.x); acc2(s2, s3, u0.y);
        acc2(s0, s1, u1.x); acc2(s2, s3, u1.y);
        acc2(s0, s1, u2.x); acc2(s2, s3, u2.y);
        acc2(s0, s1, u3.x); acc2(s2, s3, u3.y);
    }
    for (; t < m; ++t) {
        long long a0 = (long long)ap[8 * t];
        uint2 u0 = *(const uint2*)(y + a0 * 32 + 4 * q);
        acc2(s0, s1, u0.x); acc2(s2, s3, u0.y);
    }
}

// Merged layer-2 combine: out = relu(gather_mean(f16 y) + b + z) where z was
// pre-written into d_out by gc1fused. One wave per node.
__global__ __launch_bounds__(256) void gc2all(
        const unsigned short* __restrict__ ys16, const unsigned short* __restrict__ yv16,
        const int* __restrict__ nstart_s, const int* __restrict__ ndeg_s,
        const unsigned short* __restrict__ adj_s16,
        const int* __restrict__ nstart_v, const int* __restrict__ ndeg_v,
        const int* __restrict__ adj_v,
        const float* __restrict__ bl2vs, const float* __restrict__ bl2sv,
        float* __restrict__ out) {
    int b = blockIdx.x;
    bool site = (b < SB1);
    const float* bias; const int *nst, *ndg; float* o; int w, n;
    if (site) {          // site outputs gather vendor pre-projections
        w = b * 4 + (threadIdx.x >> 6); n = N_SITE;
        nst = nstart_s; ndg = ndeg_s; bias = bl2vs; o = out;
    } else {
        w = (b - SB1) * 4 + (threadIdx.x >> 6); n = N_VENDOR;
        nst = nstart_v; ndg = ndeg_v; bias = bl2sv;
        o = out + (long long)N_SITE * OUT;
    }
    if (w >= n) return;
    int lane = threadIdx.x & 63, g = lane >> 3, q = lane & 7;
    int lo = nst[w], deg = ndg[w];
    float s0 = 0.f, s1 = 0.f, s2 = 0.f, s3 = 0.f;
    if (site) gather2(yv16, adj_s16, lo, deg, g, q, s0, s1, s2, s3);
    else      gather2(ys16, adj_v,   lo, deg, g, q, s0, s1, s2, s3);
    #pragma unroll
    for (int m = 8; m <= 32; m <<= 1) {
        s0 += __shfl_xor(s0, m, 64);
        s1 += __shfl_xor(s1, m, 64);
        s2 += __shfl_xor(s2, m, 64);
        s3 += __shfl_xor(s3, m, 64);
    }
    if (g == 0) {
        float inv = 1.0f / (float)max(deg, 1);
        float4 bz = *(const float4*)(bias + 4 * q);
        long long oi = (long long)w * 32 + 4 * q;
        float4 z = *(const float4*)(o + oi);
        float4 r;
        r.x = fmaxf(fmaf(s0, inv, bz.x + z.x), 0.f);
        r.y = fmaxf(fmaf(s1, inv, bz.y + z.y), 0.f);
        r.z = fmaxf(fmaf(s2, inv, bz.z + z.z), 0.f);
        r.w = fmaxf(fmaf(s3, inv, bz.w + z.w), 0.f);
        *(float4*)(o + oi) = r;
    }
}

// ---------------------------------------------------------------------------
extern "C" void kernel_launch(void* const* d_in, const int* in_sizes, int n_in,
                              void* d_out, int out_size, void* d_ws, size_t ws_size,
                              hipStream_t stream) {
    const float* x_site      = (const float*)d_in[0];
    const float* x_vendor    = (const float*)d_in[1];
    const int*   src         = (const int*)d_in[2];
    const int*   dst         = (const int*)d_in[3];
    const float* W_site_in   = (const float*)d_in[4];
    const float* b_site_in   = (const float*)d_in[5];
    const float* W_vendor_in = (const float*)d_in[6];
    const float* b_vendor_in = (const float*)d_in[7];
    const float* Wl1sv = (const float*)d_in[8];
    const float* bl1sv = (const float*)d_in[9];
    const float* Wr1sv = (const float*)d_in[10];
    const float* Wl1vs = (const float*)d_in[11];
    const float* bl1vs = (const float*)d_in[12];
    const float* Wr1vs = (const float*)d_in[13];
    const float* Wl2sv = (const float*)d_in[14];
    const float* bl2sv = (const float*)d_in[15];
    const float* Wr2sv = (const float*)d_in[16];
    const float* Wl2vs = (const float*)d_in[17];
    const float* bl2vs = (const float*)d_in[18];
    const float* Wr2vs = (const float*)d_in[19];

    // Guard: never write past harness scratch (overrun can kill the container).
    if (ws_size < (size_t)WS_WORDS * 4) return;

    int*   wi  = (int*)d_ws;
    float* wf  = (float*)d_ws;
    float* out = (float*)d_out;

    int* nstart_s = wi + I_NSTART_S;
    int* ndeg_s   = wi + I_NDEG_S;
    int* nstart_v = wi + I_NSTART_V;
    int* ndeg_v   = wi + I_NDEG_V;
    int* gcur     = wi + I_GCUR;
    int* adj_v    = wi + I_ADJ_V;
    unsigned short* adj_s16 = (unsigned short*)(wi + I_ADJ_S);
    unsigned* pairs_s = (unsigned*)(wi + A_PAIRS_S);
    unsigned* pairs_v = (unsigned*)(wi + A_PAIRS_V);
    unsigned short* ys16 = (unsigned short*)(wf + F_Y16);
    unsigned short* yv16 = ys16 + (long long)N_SITE * 32;
    unsigned short* xsp  = (unsigned short*)(wf + F_PAD);
    unsigned short* xvp  = xsp + (long long)N_SITE * 16;
    float* fused = wf + F_FUSED;

    // zero bucket cursors (ws not re-poisoned between replays; zero every call)
    hipMemsetAsync(gcur, 0, (size_t)(NBUK_S + NBUK_V) * sizeof(int), stream);

    // merged pad + weight-fold
    prep<<<(PADTOT + 4352 + 255) / 256, 256, 0, stream>>>(
        x_site, x_vendor, xsp, xvp,
        W_site_in, b_site_in, W_vendor_in, b_vendor_in,
        Wl1sv, Wr1sv, Wl1vs, Wr1vs, fused);

    // --- CSR build: fixed-capacity buckets, one edge pass + in-bucket sort ---
    scatter_res<<<NBLK, 256, 0, stream>>>(src, dst, gcur, pairs_s, pairs_v);
    stage2both<<<NBUK_S + NBUK_V, 256, 0, stream>>>(pairs_s, pairs_v, gcur,
                                                    nstart_s, ndeg_s,
                                                    nstart_v, ndeg_v,
                                                    adj_s16, adj_v);

    // --- layer 1 + layer-2 projection, fully fused (both directions) ---
    gc1fused<<<NS_BLK + NV_BLK, 256, 0, stream>>>(
        xsp, xvp, x_site, x_vendor,
        nstart_s, ndeg_s, adj_s16, nstart_v, ndeg_v, adj_v,
        fused, bl1vs, bl1sv, Wl2sv, Wr2vs, Wl2vs, Wr2sv,
        ys16, yv16, out);

    // --- layer 2: merged gather+mean+bias+self+relu ---
    gc2all<<<SB1 + VB1, 256, 0, stream>>>(ys16, yv16,
                                          nstart_s, ndeg_s, adj_s16,
                                          nstart_v, ndeg_v, adj_v,
                                          bl2vs, bl2sv, out);

    (void)in_sizes; (void)n_in; (void)out_size;
}